// Round 10
// baseline (921.469 us; speedup 1.0000x reference)
//
#include <hip/hip_runtime.h>
#include <cstdint>
#include <cstddef>

// ---------------------------------------------------------------------------
// CADGroupingGNN: 3x GCNConv(128->128) + MLP classifier, N=50000, E=800000.
// Round 10: XCD-sliced aggregation. Agg is past-L2-traffic bound (each XCD
// pulls all 25.6MB of h; 8x205MB floor at ~3.6TB/s L3 service). Split the
// 128 channels into 8 slices of 16; slice = blockIdx%8 pins each slice to
// one XCD (round-robin dispatch), shrinking the per-XCD gather set to
// 3.2MB < 4MiB L2 -> gathers become L2-resident. fp32 everywhere (bf16/fp16
// rejected: snorm~1e4+ amplification makes logits cancellation-dominated).
// ---------------------------------------------------------------------------

__global__ __launch_bounds__(256) void k_init(int* __restrict__ cnt, int n) {
  int i = blockIdx.x * 256 + threadIdx.x;
  if (i < n) cnt[i] = 0;
}

// in-degree histogram; returned old count = edge's slot within its bucket
__global__ __launch_bounds__(256) void k_hist(
    const int* __restrict__ col, int* __restrict__ cnt,
    int* __restrict__ rank, int E) {
  int e = blockIdx.x * 256 + threadIdx.x;
  if (e < E) rank[e] = atomicAdd(&cnt[col[e]], 1);
}

// ---- exclusive scan of cnt[] over N elements (3 kernels) ----
__global__ __launch_bounds__(256) void k_scan1(
    const int* __restrict__ cnt, int* __restrict__ start,
    int* __restrict__ bsum, int n) {
  __shared__ int s[256];
  int t = threadIdx.x, idx = blockIdx.x * 256 + t;
  s[t] = (idx < n) ? cnt[idx] : 0;
  for (int d = 1; d < 256; d <<= 1) {
    __syncthreads();
    int x = (t >= d) ? s[t - d] : 0;
    __syncthreads();
    s[t] += x;
  }
  __syncthreads();
  if (idx < n) start[idx + 1] = s[t];          // inclusive, per-block
  if (t == 255) bsum[blockIdx.x] = s[255];
}

__global__ __launch_bounds__(256) void k_scan2(int* __restrict__ bsum, int nb) {
  __shared__ int s[256];
  int t = threadIdx.x;
  s[t] = (t < nb) ? bsum[t] : 0;
  for (int d = 1; d < 256; d <<= 1) {
    __syncthreads();
    int x = (t >= d) ? s[t - d] : 0;
    __syncthreads();
    s[t] += x;
  }
  __syncthreads();
  if (t < nb) bsum[t] = s[t];                  // inclusive block sums
}

__global__ __launch_bounds__(256) void k_scan3(
    int* __restrict__ start, const int* __restrict__ bsum, int n) {
  int b = blockIdx.x, idx = b * 256 + threadIdx.x;
  if (idx < n) {
    int off = (b > 0) ? bsum[b - 1] : 0;
    start[idx + 1] += off;
    if (idx == 0) start[0] = 0;
  }
}

// atomic-free bucket fill: p = start[col] + rank
__global__ __launch_bounds__(256) void k_fill(
    const int* __restrict__ attr, const float* __restrict__ emb,
    const int* __restrict__ row, const int* __restrict__ col,
    const int* __restrict__ rank, const int* __restrict__ start,
    int* __restrict__ srcs, float* __restrict__ ew_s, int E) {
  int e = blockIdx.x * 256 + threadIdx.x;
  if (e < E) {
    int p = start[col[e]] + rank[e];
    srcs[p] = row[e];
    ew_s[p] = emb[attr[e]];
  }
}

// per-node deterministic degree sum -> dinv, snorm
__global__ __launch_bounds__(256) void k_deg_csr(
    const int* __restrict__ start, const float* __restrict__ ew_s,
    float* __restrict__ dinv, float* __restrict__ snorm, int n) {
  int i = blockIdx.x * 256 + threadIdx.x;
  if (i >= n) return;
  int s = start[i], e = start[i + 1];
  float d = 1.0f;                              // self-loop weight
  for (int p = s; p < e; ++p) d += ew_s[p];
  float v = d > 0.f ? rsqrtf(d) : 0.f;
  dinv[i] = v;
  snorm[i] = v * v;
}

// per-node in-place weight normalization: ew_s[p] *= dinv[src]*dinv[i]
__global__ __launch_bounds__(256) void k_wts_csr(
    const int* __restrict__ start, const int* __restrict__ srcs,
    const float* __restrict__ dinv, float* __restrict__ ew_s, int n) {
  int i = blockIdx.x * 256 + threadIdx.x;
  if (i >= n) return;
  int s = start[i], e = start[i + 1];
  float di = dinv[i];
  for (int p = s; p < e; ++p) ew_s[p] = dinv[srcs[p]] * ew_s[p] * di;
}

__device__ __forceinline__ void agg_fma4(float s, const float4& v, float4& acc) {
  acc.x = fmaf(s, v.x, acc.x);
  acc.y = fmaf(s, v.y, acc.y);
  acc.z = fmaf(s, v.z, acc.z);
  acc.w = fmaf(s, v.w, acc.w);
}

// XCD-sliced gather-aggregate.
// slice = blockIdx%8 (16 channels, pinned to one XCD by round-robin dispatch);
// node  = (blockIdx/8)*256 + tid. Each thread: one node x 16 channels.
// out[i][c] = bias[c] + snorm[i]*h[i][c] + sum_e wts[e]*h[srcs[e]][c]
__global__ __launch_bounds__(256) void k_agg_csr(
    const float* __restrict__ h, const int* __restrict__ start,
    const int* __restrict__ srcs, const float* __restrict__ wts,
    const float* __restrict__ snorm, const float* __restrict__ bias,
    float* __restrict__ out, int n) {
  const int sl = blockIdx.x & 7;
  const int i = (blockIdx.x >> 3) * 256 + threadIdx.x;
  if (i >= n) return;
  const int b4 = sl * 4;                       // float4 offset within row
  const float4* h4 = (const float4*)h;         // row stride = 32 float4
  const float4* bias4 = (const float4*)bias;

  float4 a0 = bias4[b4 + 0], a1 = bias4[b4 + 1];
  float4 a2 = bias4[b4 + 2], a3 = bias4[b4 + 3];
  {
    const float4* hp = h4 + (size_t)i * 32 + b4;
    float sn = snorm[i];
    agg_fma4(sn, hp[0], a0); agg_fma4(sn, hp[1], a1);
    agg_fma4(sn, hp[2], a2); agg_fma4(sn, hp[3], a3);
  }

  int e = start[i];
  const int eend = start[i + 1];

  // 2-edge unrolled body: 8 independent 16B gathers in flight
  for (; e + 2 <= eend; e += 2) {
    int r0 = srcs[e], r1 = srcs[e + 1];
    float w0 = wts[e], w1 = wts[e + 1];
    const float4* p0 = h4 + (size_t)r0 * 32 + b4;
    const float4* p1 = h4 + (size_t)r1 * 32 + b4;
    float4 u0 = p0[0], u1 = p0[1], u2 = p0[2], u3 = p0[3];
    float4 v0 = p1[0], v1 = p1[1], v2 = p1[2], v3 = p1[3];
    agg_fma4(w0, u0, a0); agg_fma4(w0, u1, a1);
    agg_fma4(w0, u2, a2); agg_fma4(w0, u3, a3);
    agg_fma4(w1, v0, a0); agg_fma4(w1, v1, a1);
    agg_fma4(w1, v2, a2); agg_fma4(w1, v3, a3);
  }
  if (e < eend) {
    int r0 = srcs[e];
    float w0 = wts[e];
    const float4* p0 = h4 + (size_t)r0 * 32 + b4;
    agg_fma4(w0, p0[0], a0); agg_fma4(w0, p0[1], a1);
    agg_fma4(w0, p0[2], a2); agg_fma4(w0, p0[3], a3);
  }

  float4* op = (float4*)out + (size_t)i * 32 + b4;
  op[0] = a0; op[1] = a1; op[2] = a2; op[3] = a3;
}

// GEMM: out[M x HOUT] = act( f(A[M x 128]) @ W[128 x HOUT] + bias )
// BN=64 col tiles; persistent blocks (W staged once); 2 blocks/CU.
// ACT: 0 none, 1 relu, 2 sigmoid. RELU_IN: relu applied to A on load.
template <int HOUT, int ACT, bool RELU_IN>
__global__ __launch_bounds__(256, 2) void k_gemm(
    const float* __restrict__ A, const float* __restrict__ W,
    const float* __restrict__ bias, float* __restrict__ out, int M) {
  constexpr int NCT = HOUT / 64;   // column tiles
  constexpr int W4R = HOUT / 4;    // float4 per W row
  __shared__ float Ws[128 * 64];   // 32 KB: this block's 64-col slice of W
  __shared__ float Xs[64][132];    // 33 KB

  const int t = threadIdx.x;
  const int ct = blockIdx.x % NCT;
  const int rt0 = blockIdx.x / NCT;
  const int rstride = gridDim.x / NCT;
  const int ntiles = (M + 63) >> 6;

  // stage Ws: 2048 float4
  for (int i = t; i < 128 * 16; i += 256) {
    int k = i >> 4, j4 = i & 15;
    ((float4*)Ws)[i] = ((const float4*)W)[k * W4R + ct * 16 + j4];
  }

  const int tc = t & 15;           // 16 column groups (4 cols each)
  const int tr = t >> 4;           // 16 row groups (4 rows each)
  const float4* A4 = (const float4*)A;

  for (int rt = rt0; rt < ntiles; rt += rstride) {
    __syncthreads();               // prev compute done (and Ws staged, 1st iter)
    const int m0 = rt << 6;
    for (int i = t; i < 64 * 32; i += 256) {
      int r = i >> 5, c4 = i & 31;
      int gr = m0 + r;
      float4 v = make_float4(0.f, 0.f, 0.f, 0.f);
      if (gr < M) v = A4[(size_t)gr * 32 + c4];
      if (RELU_IN) {
        v.x = fmaxf(v.x, 0.f); v.y = fmaxf(v.y, 0.f);
        v.z = fmaxf(v.z, 0.f); v.w = fmaxf(v.w, 0.f);
      }
      *(float4*)&Xs[r][c4 * 4] = v;
    }
    __syncthreads();

    float acc[4][4];
#pragma unroll
    for (int rr = 0; rr < 4; ++rr)
      acc[rr][0] = acc[rr][1] = acc[rr][2] = acc[rr][3] = 0.f;

#pragma unroll 4
    for (int k4 = 0; k4 < 32; ++k4) {
      float4 wv[4], av[4];
#pragma unroll
      for (int kk = 0; kk < 4; ++kk)
        wv[kk] = ((const float4*)Ws)[(k4 * 4 + kk) * 16 + tc];
#pragma unroll
      for (int rr = 0; rr < 4; ++rr)
        av[rr] = *(const float4*)&Xs[tr * 4 + rr][k4 * 4];
#pragma unroll
      for (int rr = 0; rr < 4; ++rr) {
        acc[rr][0] = fmaf(av[rr].x, wv[0].x, acc[rr][0]);
        acc[rr][1] = fmaf(av[rr].x, wv[0].y, acc[rr][1]);
        acc[rr][2] = fmaf(av[rr].x, wv[0].z, acc[rr][2]);
        acc[rr][3] = fmaf(av[rr].x, wv[0].w, acc[rr][3]);
        acc[rr][0] = fmaf(av[rr].y, wv[1].x, acc[rr][0]);
        acc[rr][1] = fmaf(av[rr].y, wv[1].y, acc[rr][1]);
        acc[rr][2] = fmaf(av[rr].y, wv[1].z, acc[rr][2]);
        acc[rr][3] = fmaf(av[rr].y, wv[1].w, acc[rr][3]);
        acc[rr][0] = fmaf(av[rr].z, wv[2].x, acc[rr][0]);
        acc[rr][1] = fmaf(av[rr].z, wv[2].y, acc[rr][1]);
        acc[rr][2] = fmaf(av[rr].z, wv[2].z, acc[rr][2]);
        acc[rr][3] = fmaf(av[rr].z, wv[2].w, acc[rr][3]);
        acc[rr][0] = fmaf(av[rr].w, wv[3].x, acc[rr][0]);
        acc[rr][1] = fmaf(av[rr].w, wv[3].y, acc[rr][1]);
        acc[rr][2] = fmaf(av[rr].w, wv[3].z, acc[rr][2]);
        acc[rr][3] = fmaf(av[rr].w, wv[3].w, acc[rr][3]);
      }
    }

#pragma unroll
    for (int rr = 0; rr < 4; ++rr) {
      int gr = m0 + tr * 4 + rr;
      if (gr >= M) continue;
      float4 v = make_float4(acc[rr][0], acc[rr][1], acc[rr][2], acc[rr][3]);
      if (bias) {
        const float4 bv = *(const float4*)&bias[ct * 64 + tc * 4];
        v.x += bv.x; v.y += bv.y; v.z += bv.z; v.w += bv.w;
      }
      if (ACT == 1) {
        v.x = fmaxf(v.x, 0.f); v.y = fmaxf(v.y, 0.f);
        v.z = fmaxf(v.z, 0.f); v.w = fmaxf(v.w, 0.f);
      } else if (ACT == 2) {
        v.x = 1.f / (1.f + __expf(-v.x));
        v.y = 1.f / (1.f + __expf(-v.y));
        v.z = 1.f / (1.f + __expf(-v.z));
        v.w = 1.f / (1.f + __expf(-v.w));
      }
      ((float4*)out)[(size_t)gr * W4R + ct * 16 + tc] = v;
    }
  }
}

extern "C" void kernel_launch(void* const* d_in, const int* in_sizes, int n_in,
                              void* d_out, int out_size, void* d_ws, size_t ws_size,
                              hipStream_t stream) {
  const float* x        = (const float*)d_in[0];
  const float* edge_emb = (const float*)d_in[1];
  const float* W1 = (const float*)d_in[2];  const float* b1 = (const float*)d_in[3];
  const float* W2 = (const float*)d_in[4];  const float* b2 = (const float*)d_in[5];
  const float* W3 = (const float*)d_in[6];  const float* b3 = (const float*)d_in[7];
  const float* cW1 = (const float*)d_in[8]; const float* cb1 = (const float*)d_in[9];
  const float* cW2 = (const float*)d_in[10]; const float* cb2 = (const float*)d_in[11];
  const int* eidx  = (const int*)d_in[12];
  const int* eattr = (const int*)d_in[13];

  const int N = in_sizes[0] / 128;
  const int E = in_sizes[13];
  const int* row = eidx;        // edge_index[0] = source
  const int* col = eidx + E;    // edge_index[1] = target

  float* out = (float*)d_out;

  // workspace layout, 16B-aligned slots (element counts rounded to x4)
  size_t off = 0;
  auto alloc4 = [&](size_t n) { size_t o = off; off += (n + 3) & ~(size_t)3; return o; };
  float* wsf = (float*)d_ws;
  int*   wsi = (int*)d_ws;

  float* dinv   = wsf + alloc4(N);
  float* snorm  = wsf + alloc4(N);
  int*   cnt    = wsi + alloc4(N);
  int*   start  = wsi + alloc4(N + 1);
  int*   bsum   = wsi + alloc4(256);
  int*   rank   = wsi + alloc4(E);
  int*   srcs   = wsi + alloc4(E);
  float* wts    = wsf + alloc4(E);   // raw ew, normalized in place
  float* bufA   = wsf + alloc4((size_t)N * 128);
  float* bufB   = wsf + alloc4((size_t)N * 128);

  const int gN  = (N + 255) / 256;
  const int gE  = (E + 255) / 256;
  const int gA  = 8 * gN;            // 8 channel-slices x node blocks
  const int nb  = gN;  // scan blocks
  const int gGemm = 512;   // persistent: 2 blocks/CU

  // ---- graph preprocessing (once, reused by all 3 layers) ----
  k_init<<<gN, 256, 0, stream>>>(cnt, N);
  k_hist<<<gE, 256, 0, stream>>>(col, cnt, rank, E);
  k_scan1<<<nb, 256, 0, stream>>>(cnt, start, bsum, N);
  k_scan2<<<1, 256, 0, stream>>>(bsum, nb);
  k_scan3<<<nb, 256, 0, stream>>>(start, bsum, N);
  k_fill<<<gE, 256, 0, stream>>>(eattr, edge_emb, row, col, rank, start,
                                 srcs, wts, E);
  k_deg_csr<<<gN, 256, 0, stream>>>(start, wts, dinv, snorm, N);
  k_wts_csr<<<gN, 256, 0, stream>>>(start, srcs, dinv, wts, N);

  // ---- layer 1 ----
  k_gemm<128, 0, false><<<gGemm, 256, 0, stream>>>(x, W1, nullptr, bufA, N);
  k_agg_csr<<<gA, 256, 0, stream>>>(bufA, start, srcs, wts, snorm, b1, bufB, N);
  // ---- layer 2 (relu fused into GEMM input load) ----
  k_gemm<128, 0, true><<<gGemm, 256, 0, stream>>>(bufB, W2, nullptr, bufA, N);
  k_agg_csr<<<gA, 256, 0, stream>>>(bufA, start, srcs, wts, snorm, b2, bufB, N);
  // ---- layer 3 ----
  k_gemm<128, 0, true><<<gGemm, 256, 0, stream>>>(bufB, W3, nullptr, bufA, N);
  k_agg_csr<<<gA, 256, 0, stream>>>(bufA, start, srcs, wts, snorm, b3, bufB, N);

  // ---- classifier ----
  k_gemm<128, 1, true><<<gGemm, 256, 0, stream>>>(bufB, cW1, cb1, bufA, N);
  k_gemm<64, 2, false><<<gGemm, 256, 0, stream>>>(bufA, cW2, cb2, out, N);
}

// Round 11
// 617.972 us; speedup vs baseline: 1.4911x; 1.4911x over previous
//
#include <hip/hip_runtime.h>
#include <cstdint>
#include <cstddef>

// ---------------------------------------------------------------------------
// CADGroupingGNN: 3x GCNConv(128->128) + MLP classifier, N=50000, E=800000.
// Round 11: wave-specialized fusion. Revert agg internals to the proven
// round-6 pattern, but run it INSIDE the consumer GEMM: per block (512 thr,
// 1 block/CU, 130KB LDS), waves 4-7 aggregate tile j into Xs[j&1] (memory
// pipe) while waves 0-3 GEMM tile j-1 from Xs[(j-1)&1] (VALU pipe).
// Hides the ~25us GEMM under the ~69us service-bound agg per layer, and
// removes the 51MB bufB round-trip per layer. fp32 everywhere (mandatory).
// ---------------------------------------------------------------------------

__global__ __launch_bounds__(256) void k_init(int* __restrict__ cnt, int n) {
  int i = blockIdx.x * 256 + threadIdx.x;
  if (i < n) cnt[i] = 0;
}

// in-degree histogram; returned old count = edge's slot within its bucket
__global__ __launch_bounds__(256) void k_hist(
    const int* __restrict__ col, int* __restrict__ cnt,
    int* __restrict__ rank, int E) {
  int e = blockIdx.x * 256 + threadIdx.x;
  if (e < E) rank[e] = atomicAdd(&cnt[col[e]], 1);
}

// ---- exclusive scan of cnt[] over N elements (3 kernels) ----
__global__ __launch_bounds__(256) void k_scan1(
    const int* __restrict__ cnt, int* __restrict__ start,
    int* __restrict__ bsum, int n) {
  __shared__ int s[256];
  int t = threadIdx.x, idx = blockIdx.x * 256 + t;
  s[t] = (idx < n) ? cnt[idx] : 0;
  for (int d = 1; d < 256; d <<= 1) {
    __syncthreads();
    int x = (t >= d) ? s[t - d] : 0;
    __syncthreads();
    s[t] += x;
  }
  __syncthreads();
  if (idx < n) start[idx + 1] = s[t];          // inclusive, per-block
  if (t == 255) bsum[blockIdx.x] = s[255];
}

__global__ __launch_bounds__(256) void k_scan2(int* __restrict__ bsum, int nb) {
  __shared__ int s[256];
  int t = threadIdx.x;
  s[t] = (t < nb) ? bsum[t] : 0;
  for (int d = 1; d < 256; d <<= 1) {
    __syncthreads();
    int x = (t >= d) ? s[t - d] : 0;
    __syncthreads();
    s[t] += x;
  }
  __syncthreads();
  if (t < nb) bsum[t] = s[t];                  // inclusive block sums
}

__global__ __launch_bounds__(256) void k_scan3(
    int* __restrict__ start, const int* __restrict__ bsum, int n) {
  int b = blockIdx.x, idx = b * 256 + threadIdx.x;
  if (idx < n) {
    int off = (b > 0) ? bsum[b - 1] : 0;
    start[idx + 1] += off;
    if (idx == 0) start[0] = 0;
  }
}

// atomic-free bucket fill: p = start[col] + rank
__global__ __launch_bounds__(256) void k_fill(
    const int* __restrict__ attr, const float* __restrict__ emb,
    const int* __restrict__ row, const int* __restrict__ col,
    const int* __restrict__ rank, const int* __restrict__ start,
    int* __restrict__ srcs, float* __restrict__ ew_s, int E) {
  int e = blockIdx.x * 256 + threadIdx.x;
  if (e < E) {
    int p = start[col[e]] + rank[e];
    srcs[p] = row[e];
    ew_s[p] = emb[attr[e]];
  }
}

// per-node deterministic degree sum -> dinv, snorm
__global__ __launch_bounds__(256) void k_deg_csr(
    const int* __restrict__ start, const float* __restrict__ ew_s,
    float* __restrict__ dinv, float* __restrict__ snorm, int n) {
  int i = blockIdx.x * 256 + threadIdx.x;
  if (i >= n) return;
  int s = start[i], e = start[i + 1];
  float d = 1.0f;                              // self-loop weight
  for (int p = s; p < e; ++p) d += ew_s[p];
  float v = d > 0.f ? rsqrtf(d) : 0.f;
  dinv[i] = v;
  snorm[i] = v * v;
}

// per-node in-place weight normalization: ew_s[p] *= dinv[src]*dinv[i]
__global__ __launch_bounds__(256) void k_wts_csr(
    const int* __restrict__ start, const int* __restrict__ srcs,
    const float* __restrict__ dinv, float* __restrict__ ew_s, int n) {
  int i = blockIdx.x * 256 + threadIdx.x;
  if (i >= n) return;
  int s = start[i], e = start[i + 1];
  float di = dinv[i];
  for (int p = s; p < e; ++p) ew_s[p] = dinv[srcs[p]] * ew_s[p] * di;
}

__device__ __forceinline__ void agg_fma(float s, const float4& v, float4& acc) {
  acc.x = fmaf(s, v.x, acc.x);
  acc.y = fmaf(s, v.y, acc.y);
  acc.z = fmaf(s, v.z, acc.z);
  acc.w = fmaf(s, v.w, acc.w);
}

// round-6 proven 32-lane node aggregate: returns relu(bias + snorm*h[i] + sum)
__device__ __forceinline__ float4 agg_node(
    const float4* __restrict__ h4, const int* __restrict__ start,
    const int* __restrict__ srcs, const float* __restrict__ wts,
    const float* __restrict__ snorm, const float* __restrict__ bias4,
    int i, int lane) {
  float4 acc = ((const float4*)bias4)[lane];
  float sn = snorm[i];
  float4 hv = h4[(size_t)i * 32 + lane];
  agg_fma(sn, hv, acc);

  int e = start[i], eend = start[i + 1];
  while (e < eend && (e & 3)) {                 // align to 4
    float4 v = h4[(size_t)srcs[e] * 32 + lane];
    agg_fma(wts[e], v, acc);
    ++e;
  }
  for (; e + 8 <= eend; e += 8) {               // 8-deep pipeline
    int4   s0 = *(const int4*)&srcs[e];
    int4   s1 = *(const int4*)&srcs[e + 4];
    float4 w0 = *(const float4*)&wts[e];
    float4 w1 = *(const float4*)&wts[e + 4];
    float4 v0 = h4[(size_t)s0.x * 32 + lane];
    float4 v1 = h4[(size_t)s0.y * 32 + lane];
    float4 v2 = h4[(size_t)s0.z * 32 + lane];
    float4 v3 = h4[(size_t)s0.w * 32 + lane];
    float4 v4 = h4[(size_t)s1.x * 32 + lane];
    float4 v5 = h4[(size_t)s1.y * 32 + lane];
    float4 v6 = h4[(size_t)s1.z * 32 + lane];
    float4 v7 = h4[(size_t)s1.w * 32 + lane];
    agg_fma(w0.x, v0, acc); agg_fma(w0.y, v1, acc);
    agg_fma(w0.z, v2, acc); agg_fma(w0.w, v3, acc);
    agg_fma(w1.x, v4, acc); agg_fma(w1.y, v5, acc);
    agg_fma(w1.z, v6, acc); agg_fma(w1.w, v7, acc);
  }
  if (e + 4 <= eend) {
    int4   s0 = *(const int4*)&srcs[e];
    float4 w0 = *(const float4*)&wts[e];
    float4 v0 = h4[(size_t)s0.x * 32 + lane];
    float4 v1 = h4[(size_t)s0.y * 32 + lane];
    float4 v2 = h4[(size_t)s0.z * 32 + lane];
    float4 v3 = h4[(size_t)s0.w * 32 + lane];
    agg_fma(w0.x, v0, acc); agg_fma(w0.y, v1, acc);
    agg_fma(w0.z, v2, acc); agg_fma(w0.w, v3, acc);
    e += 4;
  }
  for (; e < eend; ++e) {
    float4 v = h4[(size_t)srcs[e] * 32 + lane];
    agg_fma(wts[e], v, acc);
  }
  acc.x = fmaxf(acc.x, 0.f); acc.y = fmaxf(acc.y, 0.f);
  acc.z = fmaxf(acc.z, 0.f); acc.w = fmaxf(acc.w, 0.f);
  return acc;
}

// Fused: h_out = act( relu(agg(h_in)) @ W  [+ gbias] )
// 512 threads, 1 block/CU. Waves 4-7 produce Xs tiles (agg); waves 0-3
// consume (GEMM 64rows x 128cols). Double-buffered Xs.
// GACT: 0 = plain (no gemm bias), 1 = +gbias then relu.
template <int GACT>
__global__ __launch_bounds__(512, 1) void k_agg_gemm(
    const float* __restrict__ h_in, const int* __restrict__ start,
    const int* __restrict__ srcs, const float* __restrict__ wts,
    const float* __restrict__ snorm, const float* __restrict__ abias,
    const float* __restrict__ W, const float* __restrict__ gbias,
    float* __restrict__ h_out, int n) {
  __shared__ float Ws[128 * 128];      // 64 KB
  __shared__ float Xs[2][64][132];     // 66 KB (528B rows, 16B aligned)

  const int t = threadIdx.x;
  // stage full W (4096 float4)
  for (int i = t; i < 128 * 32; i += 512)
    ((float4*)Ws)[i] = ((const float4*)W)[i];

  const int ntiles = (n + 63) >> 6;
  const int b = blockIdx.x;
  const int stride = gridDim.x;
  const int nj = (b < ntiles) ? ((ntiles - 1 - b) / stride + 1) : 0;
  const float4* h4 = (const float4*)h_in;

  __syncthreads();   // Ws ready

  for (int j = 0; j <= nj; ++j) {
    if (t >= 256) {
      // ---- producers: aggregate tile j into Xs[j&1] ----
      if (j < nj) {
        const int tile = b + j * stride;
        const int base = tile << 6;
        const int u = t - 256;
        const int g = u >> 5;                  // 8 groups
        const int lane = u & 31;
#pragma unroll
        for (int jj = 0; jj < 8; ++jj) {
          int r = g + (jj << 3);               // spread nodes across groups
          int i = base + r;
          float4 acc;
          if (i < n) {
            acc = agg_node(h4, start, srcs, wts, snorm, abias, i, lane);
          } else {
            acc = make_float4(0.f, 0.f, 0.f, 0.f);
          }
          *(float4*)&Xs[j & 1][r][lane * 4] = acc;
        }
      }
    } else {
      // ---- consumers: GEMM tile j-1 from Xs[(j-1)&1] ----
      if (j > 0) {
        const int tile = b + (j - 1) * stride;
        const int base = tile << 6;
        const int pb = (j - 1) & 1;
        const int tc = t & 15;                 // 8 cols (2 float4)
        const int tr = t >> 4;                 // 4 rows
        float4 acc[4][2];
#pragma unroll
        for (int rr = 0; rr < 4; ++rr) {
          acc[rr][0] = make_float4(0.f, 0.f, 0.f, 0.f);
          acc[rr][1] = make_float4(0.f, 0.f, 0.f, 0.f);
        }
#pragma unroll 2
        for (int k4 = 0; k4 < 32; ++k4) {
          float4 av[4];
#pragma unroll
          for (int rr = 0; rr < 4; ++rr)
            av[rr] = *(const float4*)&Xs[pb][tr * 4 + rr][k4 * 4];
#pragma unroll
          for (int kk = 0; kk < 4; ++kk) {
            const float* wr = &Ws[(k4 * 4 + kk) * 128 + tc * 8];
            float4 w0 = *(const float4*)wr;
            float4 w1 = *(const float4*)(wr + 4);
#pragma unroll
            for (int rr = 0; rr < 4; ++rr) {
              float a = (kk == 0) ? av[rr].x : (kk == 1) ? av[rr].y
                       : (kk == 2) ? av[rr].z : av[rr].w;
              acc[rr][0].x = fmaf(a, w0.x, acc[rr][0].x);
              acc[rr][0].y = fmaf(a, w0.y, acc[rr][0].y);
              acc[rr][0].z = fmaf(a, w0.z, acc[rr][0].z);
              acc[rr][0].w = fmaf(a, w0.w, acc[rr][0].w);
              acc[rr][1].x = fmaf(a, w1.x, acc[rr][1].x);
              acc[rr][1].y = fmaf(a, w1.y, acc[rr][1].y);
              acc[rr][1].z = fmaf(a, w1.z, acc[rr][1].z);
              acc[rr][1].w = fmaf(a, w1.w, acc[rr][1].w);
            }
          }
        }
#pragma unroll
        for (int rr = 0; rr < 4; ++rr) {
          int gr = base + tr * 4 + rr;
          if (gr >= n) continue;
          float4 v0 = acc[rr][0], v1 = acc[rr][1];
          if (GACT == 1) {
            const float4 g0 = ((const float4*)gbias)[tc * 2];
            const float4 g1 = ((const float4*)gbias)[tc * 2 + 1];
            v0.x = fmaxf(v0.x + g0.x, 0.f); v0.y = fmaxf(v0.y + g0.y, 0.f);
            v0.z = fmaxf(v0.z + g0.z, 0.f); v0.w = fmaxf(v0.w + g0.w, 0.f);
            v1.x = fmaxf(v1.x + g1.x, 0.f); v1.y = fmaxf(v1.y + g1.y, 0.f);
            v1.z = fmaxf(v1.z + g1.z, 0.f); v1.w = fmaxf(v1.w + g1.w, 0.f);
          }
          ((float4*)h_out)[(size_t)gr * 32 + tc * 2]     = v0;
          ((float4*)h_out)[(size_t)gr * 32 + tc * 2 + 1] = v1;
        }
      }
    }
    __syncthreads();
  }
}

// GEMM: out[M x HOUT] = act( f(A[M x 128]) @ W[128 x HOUT] + bias )
// BN=64 col tiles; persistent blocks (W staged once); 2 blocks/CU.
// ACT: 0 none, 1 relu, 2 sigmoid. RELU_IN: relu applied to A on load.
template <int HOUT, int ACT, bool RELU_IN>
__global__ __launch_bounds__(256, 2) void k_gemm(
    const float* __restrict__ A, const float* __restrict__ W,
    const float* __restrict__ bias, float* __restrict__ out, int M) {
  constexpr int NCT = HOUT / 64;   // column tiles
  constexpr int W4R = HOUT / 4;    // float4 per W row
  __shared__ float Ws[128 * 64];   // 32 KB: this block's 64-col slice of W
  __shared__ float Xs[64][132];    // 33 KB

  const int t = threadIdx.x;
  const int ct = blockIdx.x % NCT;
  const int rt0 = blockIdx.x / NCT;
  const int rstride = gridDim.x / NCT;
  const int ntiles = (M + 63) >> 6;

  // stage Ws: 2048 float4
  for (int i = t; i < 128 * 16; i += 256) {
    int k = i >> 4, j4 = i & 15;
    ((float4*)Ws)[i] = ((const float4*)W)[k * W4R + ct * 16 + j4];
  }

  const int tc = t & 15;           // 16 column groups (4 cols each)
  const int tr = t >> 4;           // 16 row groups (4 rows each)
  const float4* A4 = (const float4*)A;

  for (int rt = rt0; rt < ntiles; rt += rstride) {
    __syncthreads();               // prev compute done (and Ws staged, 1st iter)
    const int m0 = rt << 6;
    for (int i = t; i < 64 * 32; i += 256) {
      int r = i >> 5, c4 = i & 31;
      int gr = m0 + r;
      float4 v = make_float4(0.f, 0.f, 0.f, 0.f);
      if (gr < M) v = A4[(size_t)gr * 32 + c4];
      if (RELU_IN) {
        v.x = fmaxf(v.x, 0.f); v.y = fmaxf(v.y, 0.f);
        v.z = fmaxf(v.z, 0.f); v.w = fmaxf(v.w, 0.f);
      }
      *(float4*)&Xs[r][c4 * 4] = v;
    }
    __syncthreads();

    float acc[4][4];
#pragma unroll
    for (int rr = 0; rr < 4; ++rr)
      acc[rr][0] = acc[rr][1] = acc[rr][2] = acc[rr][3] = 0.f;

#pragma unroll 4
    for (int k4 = 0; k4 < 32; ++k4) {
      float4 wv[4], av[4];
#pragma unroll
      for (int kk = 0; kk < 4; ++kk)
        wv[kk] = ((const float4*)Ws)[(k4 * 4 + kk) * 16 + tc];
#pragma unroll
      for (int rr = 0; rr < 4; ++rr)
        av[rr] = *(const float4*)&Xs[tr * 4 + rr][k4 * 4];
#pragma unroll
      for (int rr = 0; rr < 4; ++rr) {
        acc[rr][0] = fmaf(av[rr].x, wv[0].x, acc[rr][0]);
        acc[rr][1] = fmaf(av[rr].x, wv[0].y, acc[rr][1]);
        acc[rr][2] = fmaf(av[rr].x, wv[0].z, acc[rr][2]);
        acc[rr][3] = fmaf(av[rr].x, wv[0].w, acc[rr][3]);
        acc[rr][0] = fmaf(av[rr].y, wv[1].x, acc[rr][0]);
        acc[rr][1] = fmaf(av[rr].y, wv[1].y, acc[rr][1]);
        acc[rr][2] = fmaf(av[rr].y, wv[1].z, acc[rr][2]);
        acc[rr][3] = fmaf(av[rr].y, wv[1].w, acc[rr][3]);
        acc[rr][0] = fmaf(av[rr].z, wv[2].x, acc[rr][0]);
        acc[rr][1] = fmaf(av[rr].z, wv[2].y, acc[rr][1]);
        acc[rr][2] = fmaf(av[rr].z, wv[2].z, acc[rr][2]);
        acc[rr][3] = fmaf(av[rr].z, wv[2].w, acc[rr][3]);
        acc[rr][0] = fmaf(av[rr].w, wv[3].x, acc[rr][0]);
        acc[rr][1] = fmaf(av[rr].w, wv[3].y, acc[rr][1]);
        acc[rr][2] = fmaf(av[rr].w, wv[3].z, acc[rr][2]);
        acc[rr][3] = fmaf(av[rr].w, wv[3].w, acc[rr][3]);
      }
    }

#pragma unroll
    for (int rr = 0; rr < 4; ++rr) {
      int gr = m0 + tr * 4 + rr;
      if (gr >= M) continue;
      float4 v = make_float4(acc[rr][0], acc[rr][1], acc[rr][2], acc[rr][3]);
      if (bias) {
        const float4 bv = *(const float4*)&bias[ct * 64 + tc * 4];
        v.x += bv.x; v.y += bv.y; v.z += bv.z; v.w += bv.w;
      }
      if (ACT == 1) {
        v.x = fmaxf(v.x, 0.f); v.y = fmaxf(v.y, 0.f);
        v.z = fmaxf(v.z, 0.f); v.w = fmaxf(v.w, 0.f);
      } else if (ACT == 2) {
        v.x = 1.f / (1.f + __expf(-v.x));
        v.y = 1.f / (1.f + __expf(-v.y));
        v.z = 1.f / (1.f + __expf(-v.z));
        v.w = 1.f / (1.f + __expf(-v.w));
      }
      ((float4*)out)[(size_t)gr * W4R + ct * 16 + tc] = v;
    }
  }
}

extern "C" void kernel_launch(void* const* d_in, const int* in_sizes, int n_in,
                              void* d_out, int out_size, void* d_ws, size_t ws_size,
                              hipStream_t stream) {
  const float* x        = (const float*)d_in[0];
  const float* edge_emb = (const float*)d_in[1];
  const float* W1 = (const float*)d_in[2];  const float* b1 = (const float*)d_in[3];
  const float* W2 = (const float*)d_in[4];  const float* b2 = (const float*)d_in[5];
  const float* W3 = (const float*)d_in[6];  const float* b3 = (const float*)d_in[7];
  const float* cW1 = (const float*)d_in[8]; const float* cb1 = (const float*)d_in[9];
  const float* cW2 = (const float*)d_in[10]; const float* cb2 = (const float*)d_in[11];
  const int* eidx  = (const int*)d_in[12];
  const int* eattr = (const int*)d_in[13];

  const int N = in_sizes[0] / 128;
  const int E = in_sizes[13];
  const int* row = eidx;        // edge_index[0] = source
  const int* col = eidx + E;    // edge_index[1] = target

  float* out = (float*)d_out;

  // workspace layout, 16B-aligned slots (element counts rounded to x4)
  size_t off = 0;
  auto alloc4 = [&](size_t n) { size_t o = off; off += (n + 3) & ~(size_t)3; return o; };
  float* wsf = (float*)d_ws;
  int*   wsi = (int*)d_ws;

  float* dinv   = wsf + alloc4(N);
  float* snorm  = wsf + alloc4(N);
  int*   cnt    = wsi + alloc4(N);
  int*   start  = wsi + alloc4(N + 1);
  int*   bsum   = wsi + alloc4(256);
  int*   rank   = wsi + alloc4(E);
  int*   srcs   = wsi + alloc4(E);
  float* wts    = wsf + alloc4(E);   // raw ew, normalized in place
  float* bufA   = wsf + alloc4((size_t)N * 128);
  float* bufB   = wsf + alloc4((size_t)N * 128);

  const int gN  = (N + 255) / 256;
  const int gE  = (E + 255) / 256;
  const int nb  = gN;      // scan blocks
  const int gGemm = 512;   // persistent: 2 blocks/CU
  const int gFus  = 256;   // fused: 1 block/CU

  // ---- graph preprocessing (once, reused by all 3 layers) ----
  k_init<<<gN, 256, 0, stream>>>(cnt, N);
  k_hist<<<gE, 256, 0, stream>>>(col, cnt, rank, E);
  k_scan1<<<nb, 256, 0, stream>>>(cnt, start, bsum, N);
  k_scan2<<<1, 256, 0, stream>>>(bsum, nb);
  k_scan3<<<nb, 256, 0, stream>>>(start, bsum, N);
  k_fill<<<gE, 256, 0, stream>>>(eattr, edge_emb, row, col, rank, start,
                                 srcs, wts, E);
  k_deg_csr<<<gN, 256, 0, stream>>>(start, wts, dinv, snorm, N);
  k_wts_csr<<<gN, 256, 0, stream>>>(start, srcs, dinv, wts, N);

  // ---- layer 1 GEMM: h1 = x @ W1 ----
  k_gemm<128, 0, false><<<gGemm, 256, 0, stream>>>(x, W1, nullptr, bufA, N);
  // ---- layer 2 fused: h2 = relu(agg(h1)+b1) @ W2 ----
  k_agg_gemm<0><<<gFus, 512, 0, stream>>>(bufA, start, srcs, wts, snorm, b1,
                                          W2, nullptr, bufB, N);
  // ---- layer 3 fused: h3 = relu(agg(h2)+b2) @ W3 ----
  k_agg_gemm<0><<<gFus, 512, 0, stream>>>(bufB, start, srcs, wts, snorm, b2,
                                          W3, nullptr, bufA, N);
  // ---- classifier-1 fused: c1 = relu( relu(agg(h3)+b3) @ cW1 + cb1 ) ----
  k_agg_gemm<1><<<gFus, 512, 0, stream>>>(bufA, start, srcs, wts, snorm, b3,
                                          cW1, cb1, bufB, N);
  // ---- classifier-2: out = sigmoid(c1 @ cW2 + cb2) ----
  k_gemm<64, 2, false><<<gGemm, 256, 0, stream>>>(bufB, cW2, cb2, out, N);
}

// Round 13
// 479.032 us; speedup vs baseline: 1.9236x; 1.2900x over previous
//
#include <hip/hip_runtime.h>
#include <cstdint>
#include <cstddef>

// ---------------------------------------------------------------------------
// CADGroupingGNN: 3x GCNConv(128->128) + MLP classifier, N=50000, E=800000.
// Round 13: round-12 retry. __builtin_nontemporal_* needs clang ext-vector
// types, not HIP_vector_type; route the nt accesses through ext_vector
// typedefs. CSR stream reads + out stores nontemporal (keep gather h lines
// in L2). fp32 mandatory.
// ---------------------------------------------------------------------------

typedef int   intv4 __attribute__((ext_vector_type(4)));
typedef float fltv4 __attribute__((ext_vector_type(4)));

// in-degree histogram; returned old count = edge's slot within its bucket
__global__ __launch_bounds__(256) void k_hist(
    const int* __restrict__ col, int* __restrict__ cnt,
    int* __restrict__ rank, int E) {
  int e = blockIdx.x * 256 + threadIdx.x;
  if (e < E) rank[e] = atomicAdd(&cnt[col[e]], 1);
}

// ---- exclusive scan of cnt[] over N elements (3 kernels) ----
__global__ __launch_bounds__(256) void k_scan1(
    const int* __restrict__ cnt, int* __restrict__ start,
    int* __restrict__ bsum, int n) {
  __shared__ int s[256];
  int t = threadIdx.x, idx = blockIdx.x * 256 + t;
  s[t] = (idx < n) ? cnt[idx] : 0;
  for (int d = 1; d < 256; d <<= 1) {
    __syncthreads();
    int x = (t >= d) ? s[t - d] : 0;
    __syncthreads();
    s[t] += x;
  }
  __syncthreads();
  if (idx < n) start[idx + 1] = s[t];          // inclusive, per-block
  if (t == 255) bsum[blockIdx.x] = s[255];
}

__global__ __launch_bounds__(256) void k_scan2(int* __restrict__ bsum, int nb) {
  __shared__ int s[256];
  int t = threadIdx.x;
  s[t] = (t < nb) ? bsum[t] : 0;
  for (int d = 1; d < 256; d <<= 1) {
    __syncthreads();
    int x = (t >= d) ? s[t - d] : 0;
    __syncthreads();
    s[t] += x;
  }
  __syncthreads();
  if (t < nb) bsum[t] = s[t];                  // inclusive block sums
}

__global__ __launch_bounds__(256) void k_scan3(
    int* __restrict__ start, const int* __restrict__ bsum, int n) {
  int b = blockIdx.x, idx = b * 256 + threadIdx.x;
  if (idx < n) {
    int off = (b > 0) ? bsum[b - 1] : 0;
    start[idx + 1] += off;
    if (idx == 0) start[0] = 0;
  }
}

// atomic-free bucket fill: p = start[col] + rank
__global__ __launch_bounds__(256) void k_fill(
    const int* __restrict__ attr, const float* __restrict__ emb,
    const int* __restrict__ row, const int* __restrict__ col,
    const int* __restrict__ rank, const int* __restrict__ start,
    int* __restrict__ srcs, float* __restrict__ ew_s, int E) {
  int e = blockIdx.x * 256 + threadIdx.x;
  if (e < E) {
    int p = start[col[e]] + rank[e];
    srcs[p] = row[e];
    ew_s[p] = emb[attr[e]];
  }
}

// per-node deterministic degree sum -> dinv, snorm
__global__ __launch_bounds__(256) void k_deg_csr(
    const int* __restrict__ start, const float* __restrict__ ew_s,
    float* __restrict__ dinv, float* __restrict__ snorm, int n) {
  int i = blockIdx.x * 256 + threadIdx.x;
  if (i >= n) return;
  int s = start[i], e = start[i + 1];
  float d = 1.0f;                              // self-loop weight
  for (int p = s; p < e; ++p) d += ew_s[p];
  float v = d > 0.f ? rsqrtf(d) : 0.f;
  dinv[i] = v;
  snorm[i] = v * v;
}

// per-node in-place weight normalization: ew_s[p] *= dinv[src]*dinv[i]
__global__ __launch_bounds__(256) void k_wts_csr(
    const int* __restrict__ start, const int* __restrict__ srcs,
    const float* __restrict__ dinv, float* __restrict__ ew_s, int n) {
  int i = blockIdx.x * 256 + threadIdx.x;
  if (i >= n) return;
  int s = start[i], e = start[i + 1];
  float di = dinv[i];
  for (int p = s; p < e; ++p) ew_s[p] = dinv[srcs[p]] * ew_s[p] * di;
}

__device__ __forceinline__ void agg_fma(float s, const float4& v, float4& acc) {
  acc.x = fmaf(s, v.x, acc.x);
  acc.y = fmaf(s, v.y, acc.y);
  acc.z = fmaf(s, v.z, acc.z);
  acc.w = fmaf(s, v.w, acc.w);
}

// out[i][:] = bias + snorm[i]*h[i][:] + sum_e wts[e]*h[srcs[e]][:]
// 32 lanes per node, float4 per lane (128 channels). 8-deep gather pipeline.
// CSR stream reads + output stores are nontemporal (keep h lines in L2).
__global__ __launch_bounds__(256) void k_agg_csr(
    const float* __restrict__ h, const int* __restrict__ start,
    const int* __restrict__ srcs, const float* __restrict__ wts,
    const float* __restrict__ snorm, const float* __restrict__ bias,
    float* __restrict__ out, int n) {
  int tid = blockIdx.x * 256 + threadIdx.x;
  int i = tid >> 5;
  if (i >= n) return;
  int lane = tid & 31;
  const float4* h4 = (const float4*)h;
  float4 acc = ((const float4*)bias)[lane];
  float sn = snorm[i];
  float4 hv = h4[(size_t)i * 32 + lane];
  agg_fma(sn, hv, acc);

  int e = start[i], eend = start[i + 1];

  // head: advance to 4-edge alignment so int4/float4 loads are 16B-aligned
  while (e < eend && (e & 3)) {
    float w = wts[e];
    float4 v = h4[(size_t)srcs[e] * 32 + lane];
    agg_fma(w, v, acc);
    ++e;
  }

  // body: 8 edges per iteration, 2 broadcast index loads, 8 gathers in flight
  for (; e + 8 <= eend; e += 8) {
    intv4 s0 = __builtin_nontemporal_load((const intv4*)&srcs[e]);
    intv4 s1 = __builtin_nontemporal_load((const intv4*)&srcs[e + 4]);
    fltv4 w0 = __builtin_nontemporal_load((const fltv4*)&wts[e]);
    fltv4 w1 = __builtin_nontemporal_load((const fltv4*)&wts[e + 4]);
    float4 v0 = h4[(size_t)s0.x * 32 + lane];
    float4 v1 = h4[(size_t)s0.y * 32 + lane];
    float4 v2 = h4[(size_t)s0.z * 32 + lane];
    float4 v3 = h4[(size_t)s0.w * 32 + lane];
    float4 v4 = h4[(size_t)s1.x * 32 + lane];
    float4 v5 = h4[(size_t)s1.y * 32 + lane];
    float4 v6 = h4[(size_t)s1.z * 32 + lane];
    float4 v7 = h4[(size_t)s1.w * 32 + lane];
    agg_fma(w0.x, v0, acc); agg_fma(w0.y, v1, acc);
    agg_fma(w0.z, v2, acc); agg_fma(w0.w, v3, acc);
    agg_fma(w1.x, v4, acc); agg_fma(w1.y, v5, acc);
    agg_fma(w1.z, v6, acc); agg_fma(w1.w, v7, acc);
  }

  // 4-edge step
  if (e + 4 <= eend) {
    intv4 s0 = __builtin_nontemporal_load((const intv4*)&srcs[e]);
    fltv4 w0 = __builtin_nontemporal_load((const fltv4*)&wts[e]);
    float4 v0 = h4[(size_t)s0.x * 32 + lane];
    float4 v1 = h4[(size_t)s0.y * 32 + lane];
    float4 v2 = h4[(size_t)s0.z * 32 + lane];
    float4 v3 = h4[(size_t)s0.w * 32 + lane];
    agg_fma(w0.x, v0, acc); agg_fma(w0.y, v1, acc);
    agg_fma(w0.z, v2, acc); agg_fma(w0.w, v3, acc);
    e += 4;
  }

  // tail
  for (; e < eend; ++e) {
    float w = wts[e];
    float4 v = h4[(size_t)srcs[e] * 32 + lane];
    agg_fma(w, v, acc);
  }

  fltv4 o;
  o.x = acc.x; o.y = acc.y; o.z = acc.z; o.w = acc.w;
  __builtin_nontemporal_store(o, (fltv4*)out + (size_t)i * 32 + lane);
}

// GEMM: out[M x HOUT] = act( f(A[M x 128]) @ W[128 x HOUT] + bias )
// BN=64 col tiles; persistent blocks (W staged once); 2 blocks/CU.
// ACT: 0 none, 1 relu, 2 sigmoid. RELU_IN: relu applied to A on load.
template <int HOUT, int ACT, bool RELU_IN>
__global__ __launch_bounds__(256, 2) void k_gemm(
    const float* __restrict__ A, const float* __restrict__ W,
    const float* __restrict__ bias, float* __restrict__ out, int M) {
  constexpr int NCT = HOUT / 64;   // column tiles
  constexpr int W4R = HOUT / 4;    // float4 per W row
  __shared__ float Ws[128 * 64];   // 32 KB: this block's 64-col slice of W
  __shared__ float Xs[64][132];    // 33 KB

  const int t = threadIdx.x;
  const int ct = blockIdx.x % NCT;
  const int rt0 = blockIdx.x / NCT;
  const int rstride = gridDim.x / NCT;
  const int ntiles = (M + 63) >> 6;

  // stage Ws: 2048 float4
  for (int i = t; i < 128 * 16; i += 256) {
    int k = i >> 4, j4 = i & 15;
    ((float4*)Ws)[i] = ((const float4*)W)[k * W4R + ct * 16 + j4];
  }

  const int tc = t & 15;           // 16 column groups (4 cols each)
  const int tr = t >> 4;           // 16 row groups (4 rows each)
  const float4* A4 = (const float4*)A;

  for (int rt = rt0; rt < ntiles; rt += rstride) {
    __syncthreads();               // prev compute done (and Ws staged, 1st iter)
    const int m0 = rt << 6;
    for (int i = t; i < 64 * 32; i += 256) {
      int r = i >> 5, c4 = i & 31;
      int gr = m0 + r;
      float4 v = make_float4(0.f, 0.f, 0.f, 0.f);
      if (gr < M) v = A4[(size_t)gr * 32 + c4];
      if (RELU_IN) {
        v.x = fmaxf(v.x, 0.f); v.y = fmaxf(v.y, 0.f);
        v.z = fmaxf(v.z, 0.f); v.w = fmaxf(v.w, 0.f);
      }
      *(float4*)&Xs[r][c4 * 4] = v;
    }
    __syncthreads();

    float acc[4][4];
#pragma unroll
    for (int rr = 0; rr < 4; ++rr)
      acc[rr][0] = acc[rr][1] = acc[rr][2] = acc[rr][3] = 0.f;

#pragma unroll 4
    for (int k4 = 0; k4 < 32; ++k4) {
      float4 wv[4], av[4];
#pragma unroll
      for (int kk = 0; kk < 4; ++kk)
        wv[kk] = ((const float4*)Ws)[(k4 * 4 + kk) * 16 + tc];
#pragma unroll
      for (int rr = 0; rr < 4; ++rr)
        av[rr] = *(const float4*)&Xs[tr * 4 + rr][k4 * 4];
#pragma unroll
      for (int rr = 0; rr < 4; ++rr) {
        acc[rr][0] = fmaf(av[rr].x, wv[0].x, acc[rr][0]);
        acc[rr][1] = fmaf(av[rr].x, wv[0].y, acc[rr][1]);
        acc[rr][2] = fmaf(av[rr].x, wv[0].z, acc[rr][2]);
        acc[rr][3] = fmaf(av[rr].x, wv[0].w, acc[rr][3]);
        acc[rr][0] = fmaf(av[rr].y, wv[1].x, acc[rr][0]);
        acc[rr][1] = fmaf(av[rr].y, wv[1].y, acc[rr][1]);
        acc[rr][2] = fmaf(av[rr].y, wv[1].z, acc[rr][2]);
        acc[rr][3] = fmaf(av[rr].y, wv[1].w, acc[rr][3]);
        acc[rr][0] = fmaf(av[rr].z, wv[2].x, acc[rr][0]);
        acc[rr][1] = fmaf(av[rr].z, wv[2].y, acc[rr][1]);
        acc[rr][2] = fmaf(av[rr].z, wv[2].z, acc[rr][2]);
        acc[rr][3] = fmaf(av[rr].z, wv[2].w, acc[rr][3]);
        acc[rr][0] = fmaf(av[rr].w, wv[3].x, acc[rr][0]);
        acc[rr][1] = fmaf(av[rr].w, wv[3].y, acc[rr][1]);
        acc[rr][2] = fmaf(av[rr].w, wv[3].z, acc[rr][2]);
        acc[rr][3] = fmaf(av[rr].w, wv[3].w, acc[rr][3]);
      }
    }

#pragma unroll
    for (int rr = 0; rr < 4; ++rr) {
      int gr = m0 + tr * 4 + rr;
      if (gr >= M) continue;
      float4 v = make_float4(acc[rr][0], acc[rr][1], acc[rr][2], acc[rr][3]);
      if (bias) {
        const float4 bv = *(const float4*)&bias[ct * 64 + tc * 4];
        v.x += bv.x; v.y += bv.y; v.z += bv.z; v.w += bv.w;
      }
      if (ACT == 1) {
        v.x = fmaxf(v.x, 0.f); v.y = fmaxf(v.y, 0.f);
        v.z = fmaxf(v.z, 0.f); v.w = fmaxf(v.w, 0.f);
      } else if (ACT == 2) {
        v.x = 1.f / (1.f + __expf(-v.x));
        v.y = 1.f / (1.f + __expf(-v.y));
        v.z = 1.f / (1.f + __expf(-v.z));
        v.w = 1.f / (1.f + __expf(-v.w));
      }
      ((float4*)out)[(size_t)gr * W4R + ct * 16 + tc] = v;
    }
  }
}

extern "C" void kernel_launch(void* const* d_in, const int* in_sizes, int n_in,
                              void* d_out, int out_size, void* d_ws, size_t ws_size,
                              hipStream_t stream) {
  const float* x        = (const float*)d_in[0];
  const float* edge_emb = (const float*)d_in[1];
  const float* W1 = (const float*)d_in[2];  const float* b1 = (const float*)d_in[3];
  const float* W2 = (const float*)d_in[4];  const float* b2 = (const float*)d_in[5];
  const float* W3 = (const float*)d_in[6];  const float* b3 = (const float*)d_in[7];
  const float* cW1 = (const float*)d_in[8]; const float* cb1 = (const float*)d_in[9];
  const float* cW2 = (const float*)d_in[10]; const float* cb2 = (const float*)d_in[11];
  const int* eidx  = (const int*)d_in[12];
  const int* eattr = (const int*)d_in[13];

  const int N = in_sizes[0] / 128;
  const int E = in_sizes[13];
  const int* row = eidx;        // edge_index[0] = source
  const int* col = eidx + E;    // edge_index[1] = target

  float* out = (float*)d_out;

  // workspace layout, 16B-aligned slots (element counts rounded to x4)
  size_t off = 0;
  auto alloc4 = [&](size_t n) { size_t o = off; off += (n + 3) & ~(size_t)3; return o; };
  float* wsf = (float*)d_ws;
  int*   wsi = (int*)d_ws;

  float* dinv   = wsf + alloc4(N);
  float* snorm  = wsf + alloc4(N);
  int*   cnt    = wsi + alloc4(N);
  int*   start  = wsi + alloc4(N + 1);
  int*   bsum   = wsi + alloc4(256);
  int*   rank   = wsi + alloc4(E);
  int*   srcs   = wsi + alloc4(E);
  float* wts    = wsf + alloc4(E);   // raw ew, normalized in place
  float* bufA   = wsf + alloc4((size_t)N * 128);
  float* bufB   = wsf + alloc4((size_t)N * 128);

  const int gN  = (N + 255) / 256;
  const int gE  = (E + 255) / 256;
  const int gA  = (N * 32 + 255) / 256;
  const int nb  = gN;  // scan blocks
  const int gGemm = 512;   // persistent: 2 blocks/CU

  // ---- graph preprocessing (once, reused by all 3 layers) ----
  (void)hipMemsetAsync(cnt, 0, (size_t)N * sizeof(int), stream);
  k_hist<<<gE, 256, 0, stream>>>(col, cnt, rank, E);
  k_scan1<<<nb, 256, 0, stream>>>(cnt, start, bsum, N);
  k_scan2<<<1, 256, 0, stream>>>(bsum, nb);
  k_scan3<<<nb, 256, 0, stream>>>(start, bsum, N);
  k_fill<<<gE, 256, 0, stream>>>(eattr, edge_emb, row, col, rank, start,
                                 srcs, wts, E);
  k_deg_csr<<<gN, 256, 0, stream>>>(start, wts, dinv, snorm, N);
  k_wts_csr<<<gN, 256, 0, stream>>>(start, srcs, dinv, wts, N);

  // ---- layer 1 ----
  k_gemm<128, 0, false><<<gGemm, 256, 0, stream>>>(x, W1, nullptr, bufA, N);
  k_agg_csr<<<gA, 256, 0, stream>>>(bufA, start, srcs, wts, snorm, b1, bufB, N);
  // ---- layer 2 (relu fused into GEMM input load) ----
  k_gemm<128, 0, true><<<gGemm, 256, 0, stream>>>(bufB, W2, nullptr, bufA, N);
  k_agg_csr<<<gA, 256, 0, stream>>>(bufA, start, srcs, wts, snorm, b2, bufB, N);
  // ---- layer 3 ----
  k_gemm<128, 0, true><<<gGemm, 256, 0, stream>>>(bufB, W3, nullptr, bufA, N);
  k_agg_csr<<<gA, 256, 0, stream>>>(bufA, start, srcs, wts, snorm, b3, bufB, N);

  // ---- classifier ----
  k_gemm<128, 1, true><<<gGemm, 256, 0, stream>>>(bufB, cW1, cb1, bufA, N);
  k_gemm<64, 2, false><<<gGemm, 256, 0, stream>>>(bufA, cW2, cb2, out, N);
}

// Round 14
// 448.169 us; speedup vs baseline: 2.0561x; 1.0689x over previous
//
#include <hip/hip_runtime.h>
#include <cstdint>
#include <cstddef>

// ---------------------------------------------------------------------------
// CADGroupingGNN: 3x GCNConv(128->128) + MLP classifier, N=50000, E=800000.
// Round 14: revert nontemporal (r13 regression: nt store broke L2 reuse for
// the consumer GEMM). Agg = plain round-6 form (proven 69.3us floor).
// + hist folded into layer-1 GEMM as a tail (independent work, one dispatch,
//   atomic-latency hist overlaps VALU-bound GEMM).
// + edge-parallel weight normalization (replaces serial per-node loop).
// fp32 mandatory (bf16/fp16 flip saturated sigmoids, snorm~1e4 amplify).
// ---------------------------------------------------------------------------

// ---- exclusive scan of cnt[] over N elements (3 kernels) ----
__global__ __launch_bounds__(256) void k_scan1(
    const int* __restrict__ cnt, int* __restrict__ start,
    int* __restrict__ bsum, int n) {
  __shared__ int s[256];
  int t = threadIdx.x, idx = blockIdx.x * 256 + t;
  s[t] = (idx < n) ? cnt[idx] : 0;
  for (int d = 1; d < 256; d <<= 1) {
    __syncthreads();
    int x = (t >= d) ? s[t - d] : 0;
    __syncthreads();
    s[t] += x;
  }
  __syncthreads();
  if (idx < n) start[idx + 1] = s[t];          // inclusive, per-block
  if (t == 255) bsum[blockIdx.x] = s[255];
}

__global__ __launch_bounds__(256) void k_scan2(int* __restrict__ bsum, int nb) {
  __shared__ int s[256];
  int t = threadIdx.x;
  s[t] = (t < nb) ? bsum[t] : 0;
  for (int d = 1; d < 256; d <<= 1) {
    __syncthreads();
    int x = (t >= d) ? s[t - d] : 0;
    __syncthreads();
    s[t] += x;
  }
  __syncthreads();
  if (t < nb) bsum[t] = s[t];                  // inclusive block sums
}

__global__ __launch_bounds__(256) void k_scan3(
    int* __restrict__ start, const int* __restrict__ bsum, int n) {
  int b = blockIdx.x, idx = b * 256 + threadIdx.x;
  if (idx < n) {
    int off = (b > 0) ? bsum[b - 1] : 0;
    start[idx + 1] += off;
    if (idx == 0) start[0] = 0;
  }
}

// atomic-free bucket fill: p = start[col] + rank; writes src index + raw ew
__global__ __launch_bounds__(256) void k_fill(
    const int* __restrict__ attr, const float* __restrict__ emb,
    const int* __restrict__ row, const int* __restrict__ col,
    const int* __restrict__ rank, const int* __restrict__ start,
    int* __restrict__ srcs, float* __restrict__ ew_s, int E) {
  int e = blockIdx.x * 256 + threadIdx.x;
  if (e < E) {
    int p = start[col[e]] + rank[e];
    srcs[p] = row[e];
    ew_s[p] = emb[attr[e]];
  }
}

// per-node deterministic degree sum (raw ew in wts) -> dinv, snorm
__global__ __launch_bounds__(256) void k_deg_csr(
    const int* __restrict__ start, const float* __restrict__ ew_s,
    float* __restrict__ dinv, float* __restrict__ snorm, int n) {
  int i = blockIdx.x * 256 + threadIdx.x;
  if (i >= n) return;
  int s = start[i], e = start[i + 1];
  float d = 1.0f;                              // self-loop weight
  for (int p = s; p < e; ++p) d += ew_s[p];
  float v = d > 0.f ? rsqrtf(d) : 0.f;
  dinv[i] = v;
  snorm[i] = v * v;
}

// edge-parallel weight normalization: wts[p] = dinv[row]*emb*dinv[col]
__global__ __launch_bounds__(256) void k_wts_edge(
    const int* __restrict__ attr, const float* __restrict__ emb,
    const int* __restrict__ row, const int* __restrict__ col,
    const int* __restrict__ rank, const int* __restrict__ start,
    const float* __restrict__ dinv, float* __restrict__ wts, int E) {
  int e = blockIdx.x * 256 + threadIdx.x;
  if (e < E) {
    int c = col[e];
    int p = start[c] + rank[e];
    wts[p] = dinv[row[e]] * emb[attr[e]] * dinv[c];
  }
}

__device__ __forceinline__ void agg_fma(float s, const float4& v, float4& acc) {
  acc.x = fmaf(s, v.x, acc.x);
  acc.y = fmaf(s, v.y, acc.y);
  acc.z = fmaf(s, v.z, acc.z);
  acc.w = fmaf(s, v.w, acc.w);
}

// out[i][:] = bias + snorm[i]*h[i][:] + sum_e wts[e]*h[srcs[e]][:]
// 32 lanes per node, float4 per lane (128 channels). 8-deep gather pipeline.
// (round-6 proven form, plain loads/stores)
__global__ __launch_bounds__(256) void k_agg_csr(
    const float* __restrict__ h, const int* __restrict__ start,
    const int* __restrict__ srcs, const float* __restrict__ wts,
    const float* __restrict__ snorm, const float* __restrict__ bias,
    float* __restrict__ out, int n) {
  int tid = blockIdx.x * 256 + threadIdx.x;
  int i = tid >> 5;
  if (i >= n) return;
  int lane = tid & 31;
  const float4* h4 = (const float4*)h;
  float4 acc = ((const float4*)bias)[lane];
  float sn = snorm[i];
  float4 hv = h4[(size_t)i * 32 + lane];
  agg_fma(sn, hv, acc);

  int e = start[i], eend = start[i + 1];

  while (e < eend && (e & 3)) {
    float w = wts[e];
    float4 v = h4[(size_t)srcs[e] * 32 + lane];
    agg_fma(w, v, acc);
    ++e;
  }

  for (; e + 8 <= eend; e += 8) {
    int4   s0 = *(const int4*)&srcs[e];
    int4   s1 = *(const int4*)&srcs[e + 4];
    float4 w0 = *(const float4*)&wts[e];
    float4 w1 = *(const float4*)&wts[e + 4];
    float4 v0 = h4[(size_t)s0.x * 32 + lane];
    float4 v1 = h4[(size_t)s0.y * 32 + lane];
    float4 v2 = h4[(size_t)s0.z * 32 + lane];
    float4 v3 = h4[(size_t)s0.w * 32 + lane];
    float4 v4 = h4[(size_t)s1.x * 32 + lane];
    float4 v5 = h4[(size_t)s1.y * 32 + lane];
    float4 v6 = h4[(size_t)s1.z * 32 + lane];
    float4 v7 = h4[(size_t)s1.w * 32 + lane];
    agg_fma(w0.x, v0, acc); agg_fma(w0.y, v1, acc);
    agg_fma(w0.z, v2, acc); agg_fma(w0.w, v3, acc);
    agg_fma(w1.x, v4, acc); agg_fma(w1.y, v5, acc);
    agg_fma(w1.z, v6, acc); agg_fma(w1.w, v7, acc);
  }

  if (e + 4 <= eend) {
    int4   s0 = *(const int4*)&srcs[e];
    float4 w0 = *(const float4*)&wts[e];
    float4 v0 = h4[(size_t)s0.x * 32 + lane];
    float4 v1 = h4[(size_t)s0.y * 32 + lane];
    float4 v2 = h4[(size_t)s0.z * 32 + lane];
    float4 v3 = h4[(size_t)s0.w * 32 + lane];
    agg_fma(w0.x, v0, acc); agg_fma(w0.y, v1, acc);
    agg_fma(w0.z, v2, acc); agg_fma(w0.w, v3, acc);
    e += 4;
  }

  for (; e < eend; ++e) {
    float w = wts[e];
    float4 v = h4[(size_t)srcs[e] * 32 + lane];
    agg_fma(w, v, acc);
  }

  ((float4*)out)[(size_t)i * 32 + lane] = acc;
}

// GEMM: out[M x HOUT] = act( f(A[M x 128]) @ W[128 x HOUT] + bias )
// BN=64 col tiles; persistent blocks (W staged once); 2 blocks/CU.
// ACT: 0 none, 1 relu, 2 sigmoid. RELU_IN: relu on A load.
// TAIL_HIST: after the tile loop, run the edge histogram (independent work;
// overlaps atomic-latency hist with other blocks' VALU GEMM).
template <int HOUT, int ACT, bool RELU_IN, bool TAIL_HIST>
__global__ __launch_bounds__(256, 2) void k_gemm(
    const float* __restrict__ A, const float* __restrict__ W,
    const float* __restrict__ bias, float* __restrict__ out, int M,
    const int* __restrict__ hcol, int* __restrict__ hcnt,
    int* __restrict__ hrank, int E) {
  constexpr int NCT = HOUT / 64;   // column tiles
  constexpr int W4R = HOUT / 4;    // float4 per W row
  __shared__ float Ws[128 * 64];   // 32 KB
  __shared__ float Xs[64][132];    // 33 KB

  const int t = threadIdx.x;
  const int ct = blockIdx.x % NCT;
  const int rt0 = blockIdx.x / NCT;
  const int rstride = gridDim.x / NCT;
  const int ntiles = (M + 63) >> 6;

  for (int i = t; i < 128 * 16; i += 256) {
    int k = i >> 4, j4 = i & 15;
    ((float4*)Ws)[i] = ((const float4*)W)[k * W4R + ct * 16 + j4];
  }

  const int tc = t & 15;
  const int tr = t >> 4;
  const float4* A4 = (const float4*)A;

  for (int rt = rt0; rt < ntiles; rt += rstride) {
    __syncthreads();
    const int m0 = rt << 6;
    for (int i = t; i < 64 * 32; i += 256) {
      int r = i >> 5, c4 = i & 31;
      int gr = m0 + r;
      float4 v = make_float4(0.f, 0.f, 0.f, 0.f);
      if (gr < M) v = A4[(size_t)gr * 32 + c4];
      if (RELU_IN) {
        v.x = fmaxf(v.x, 0.f); v.y = fmaxf(v.y, 0.f);
        v.z = fmaxf(v.z, 0.f); v.w = fmaxf(v.w, 0.f);
      }
      *(float4*)&Xs[r][c4 * 4] = v;
    }
    __syncthreads();

    float acc[4][4];
#pragma unroll
    for (int rr = 0; rr < 4; ++rr)
      acc[rr][0] = acc[rr][1] = acc[rr][2] = acc[rr][3] = 0.f;

#pragma unroll 4
    for (int k4 = 0; k4 < 32; ++k4) {
      float4 wv[4], av[4];
#pragma unroll
      for (int kk = 0; kk < 4; ++kk)
        wv[kk] = ((const float4*)Ws)[(k4 * 4 + kk) * 16 + tc];
#pragma unroll
      for (int rr = 0; rr < 4; ++rr)
        av[rr] = *(const float4*)&Xs[tr * 4 + rr][k4 * 4];
#pragma unroll
      for (int rr = 0; rr < 4; ++rr) {
        acc[rr][0] = fmaf(av[rr].x, wv[0].x, acc[rr][0]);
        acc[rr][1] = fmaf(av[rr].x, wv[0].y, acc[rr][1]);
        acc[rr][2] = fmaf(av[rr].x, wv[0].z, acc[rr][2]);
        acc[rr][3] = fmaf(av[rr].x, wv[0].w, acc[rr][3]);
        acc[rr][0] = fmaf(av[rr].y, wv[1].x, acc[rr][0]);
        acc[rr][1] = fmaf(av[rr].y, wv[1].y, acc[rr][1]);
        acc[rr][2] = fmaf(av[rr].y, wv[1].z, acc[rr][2]);
        acc[rr][3] = fmaf(av[rr].y, wv[1].w, acc[rr][3]);
        acc[rr][0] = fmaf(av[rr].z, wv[2].x, acc[rr][0]);
        acc[rr][1] = fmaf(av[rr].z, wv[2].y, acc[rr][1]);
        acc[rr][2] = fmaf(av[rr].z, wv[2].z, acc[rr][2]);
        acc[rr][3] = fmaf(av[rr].z, wv[2].w, acc[rr][3]);
        acc[rr][0] = fmaf(av[rr].w, wv[3].x, acc[rr][0]);
        acc[rr][1] = fmaf(av[rr].w, wv[3].y, acc[rr][1]);
        acc[rr][2] = fmaf(av[rr].w, wv[3].z, acc[rr][2]);
        acc[rr][3] = fmaf(av[rr].w, wv[3].w, acc[rr][3]);
      }
    }

#pragma unroll
    for (int rr = 0; rr < 4; ++rr) {
      int gr = m0 + tr * 4 + rr;
      if (gr >= M) continue;
      float4 v = make_float4(acc[rr][0], acc[rr][1], acc[rr][2], acc[rr][3]);
      if (bias) {
        const float4 bv = *(const float4*)&bias[ct * 64 + tc * 4];
        v.x += bv.x; v.y += bv.y; v.z += bv.z; v.w += bv.w;
      }
      if (ACT == 1) {
        v.x = fmaxf(v.x, 0.f); v.y = fmaxf(v.y, 0.f);
        v.z = fmaxf(v.z, 0.f); v.w = fmaxf(v.w, 0.f);
      } else if (ACT == 2) {
        v.x = 1.f / (1.f + __expf(-v.x));
        v.y = 1.f / (1.f + __expf(-v.y));
        v.z = 1.f / (1.f + __expf(-v.z));
        v.w = 1.f / (1.f + __expf(-v.w));
      }
      ((float4*)out)[(size_t)gr * W4R + ct * 16 + tc] = v;
    }
  }

  if (TAIL_HIST) {
    // independent edge histogram; rank = slot within target bucket
    const int gsz = gridDim.x * 256;
    for (int e = blockIdx.x * 256 + t; e < E; e += gsz)
      hrank[e] = atomicAdd(&hcnt[hcol[e]], 1);
  }
}

extern "C" void kernel_launch(void* const* d_in, const int* in_sizes, int n_in,
                              void* d_out, int out_size, void* d_ws, size_t ws_size,
                              hipStream_t stream) {
  const float* x        = (const float*)d_in[0];
  const float* edge_emb = (const float*)d_in[1];
  const float* W1 = (const float*)d_in[2];  const float* b1 = (const float*)d_in[3];
  const float* W2 = (const float*)d_in[4];  const float* b2 = (const float*)d_in[5];
  const float* W3 = (const float*)d_in[6];  const float* b3 = (const float*)d_in[7];
  const float* cW1 = (const float*)d_in[8]; const float* cb1 = (const float*)d_in[9];
  const float* cW2 = (const float*)d_in[10]; const float* cb2 = (const float*)d_in[11];
  const int* eidx  = (const int*)d_in[12];
  const int* eattr = (const int*)d_in[13];

  const int N = in_sizes[0] / 128;
  const int E = in_sizes[13];
  const int* row = eidx;        // edge_index[0] = source
  const int* col = eidx + E;    // edge_index[1] = target

  float* out = (float*)d_out;

  // workspace layout, 16B-aligned slots (element counts rounded to x4)
  size_t off = 0;
  auto alloc4 = [&](size_t n) { size_t o = off; off += (n + 3) & ~(size_t)3; return o; };
  float* wsf = (float*)d_ws;
  int*   wsi = (int*)d_ws;

  float* dinv   = wsf + alloc4(N);
  float* snorm  = wsf + alloc4(N);
  int*   cnt    = wsi + alloc4(N);
  int*   start  = wsi + alloc4(N + 1);
  int*   bsum   = wsi + alloc4(256);
  int*   rank   = wsi + alloc4(E);
  int*   srcs   = wsi + alloc4(E);
  float* wts    = wsf + alloc4(E);   // raw ew (deg pass), then normalized
  float* bufA   = wsf + alloc4((size_t)N * 128);
  float* bufB   = wsf + alloc4((size_t)N * 128);

  const int gN  = (N + 255) / 256;
  const int gE  = (E + 255) / 256;
  const int gA  = (N * 32 + 255) / 256;
  const int nb  = gN;  // scan blocks
  const int gGemm = 512;   // persistent: 2 blocks/CU

  // cnt must be zero before the hist tail in the layer-1 GEMM
  (void)hipMemsetAsync(cnt, 0, (size_t)N * sizeof(int), stream);

  // ---- layer-1 GEMM + edge histogram (independent, one dispatch) ----
  k_gemm<128, 0, false, true><<<gGemm, 256, 0, stream>>>(
      x, W1, nullptr, bufA, N, col, cnt, rank, E);

  // ---- CSR build (reused by all 3 layers) ----
  k_scan1<<<nb, 256, 0, stream>>>(cnt, start, bsum, N);
  k_scan2<<<1, 256, 0, stream>>>(bsum, nb);
  k_scan3<<<nb, 256, 0, stream>>>(start, bsum, N);
  k_fill<<<gE, 256, 0, stream>>>(eattr, edge_emb, row, col, rank, start,
                                 srcs, wts, E);
  k_deg_csr<<<gN, 256, 0, stream>>>(start, wts, dinv, snorm, N);
  k_wts_edge<<<gE, 256, 0, stream>>>(eattr, edge_emb, row, col, rank, start,
                                     dinv, wts, E);

  // ---- layer 1 agg ----
  k_agg_csr<<<gA, 256, 0, stream>>>(bufA, start, srcs, wts, snorm, b1, bufB, N);
  // ---- layer 2 ----
  k_gemm<128, 0, true, false><<<gGemm, 256, 0, stream>>>(
      bufB, W2, nullptr, bufA, N, nullptr, nullptr, nullptr, 0);
  k_agg_csr<<<gA, 256, 0, stream>>>(bufA, start, srcs, wts, snorm, b2, bufB, N);
  // ---- layer 3 ----
  k_gemm<128, 0, true, false><<<gGemm, 256, 0, stream>>>(
      bufB, W3, nullptr, bufA, N, nullptr, nullptr, nullptr, 0);
  k_agg_csr<<<gA, 256, 0, stream>>>(bufA, start, srcs, wts, snorm, b3, bufB, N);

  // ---- classifier ----
  k_gemm<128, 1, true, false><<<gGemm, 256, 0, stream>>>(
      bufB, cW1, cb1, bufA, N, nullptr, nullptr, nullptr, 0);
  k_gemm<64, 2, false, false><<<gGemm, 256, 0, stream>>>(
      bufA, cW2, cb2, out, N, nullptr, nullptr, nullptr, 0);
}